// Round 1
// baseline (543.320 us; speedup 1.0000x reference)
//
#include <hip/hip_runtime.h>
#include <math.h>

// Problem constants (B=2, T=2048, D=512, H=8, hd=64, K=16, DEPTH=3)
#define TSEQ   2048
#define DM     512
#define NH     8
#define HD     64
#define KATT   16
#define NDEPTH 3
#define MROWS  4096   // B*T

typedef __attribute__((ext_vector_type(8))) short bf16x8;
typedef __attribute__((ext_vector_type(4))) float f32x4;

// f32 -> bf16 (round-to-nearest-even), bit-level, no header dependency
static __device__ __forceinline__ unsigned short f2b(float f) {
    unsigned int u = __float_as_uint(f);
    unsigned int r = (u + 0x7fffu + ((u >> 16) & 1u)) >> 16;
    return (unsigned short)r;
}

// ---------------------------------------------------------------------------
// Weight prep: W f32 [K x N] (per depth) -> Wt bf16 [N x K]. grid.z = depth.
// ---------------------------------------------------------------------------
__global__ __launch_bounds__(256) void transpose_w_kernel(
    const float* __restrict__ W, unsigned short* __restrict__ Wt, int Kd, int Nd)
{
    __shared__ float tile[32][33];
    const int n0 = blockIdx.x * 32, k0 = blockIdx.y * 32;
    const size_t off = (size_t)blockIdx.z * Kd * Nd;
    const float* Wd = W + off;
    unsigned short* Wtd = Wt + off;
    const int tx = threadIdx.x, ty = threadIdx.y;
#pragma unroll
    for (int r = 0; r < 32; r += 8)
        tile[ty + r][tx] = Wd[(size_t)(k0 + ty + r) * Nd + (n0 + tx)];
    __syncthreads();
#pragma unroll
    for (int r = 0; r < 32; r += 8)
        Wtd[(size_t)(n0 + ty + r) * Kd + (k0 + tx)] = f2b(tile[tx][ty + r]);
}

// ---------------------------------------------------------------------------
// LayerNorm: x f32 [4096 x 512] -> h bf16 [4096 x 512]. One wave per row.
// ---------------------------------------------------------------------------
__global__ __launch_bounds__(256) void ln_kernel(
    const float* __restrict__ x, const float* __restrict__ sc,
    const float* __restrict__ bi, unsigned short* __restrict__ h)
{
    const int wid  = blockIdx.x * 4 + (threadIdx.x >> 6);
    const int lane = threadIdx.x & 63;
    const float* xr = x + (size_t)wid * DM;
    const float4 v0 = *(const float4*)&xr[lane * 4];
    const float4 v1 = *(const float4*)&xr[256 + lane * 4];
    float s = v0.x + v0.y + v0.z + v0.w + v1.x + v1.y + v1.z + v1.w;
    float q = v0.x*v0.x + v0.y*v0.y + v0.z*v0.z + v0.w*v0.w
            + v1.x*v1.x + v1.y*v1.y + v1.z*v1.z + v1.w*v1.w;
#pragma unroll
    for (int off = 32; off; off >>= 1) {
        s += __shfl_xor(s, off, 64);
        q += __shfl_xor(q, off, 64);
    }
    const float mean = s * (1.0f / DM);
    const float var  = q * (1.0f / DM) - mean * mean;
    const float rs   = rsqrtf(var + 1e-5f);
    unsigned short* hr = h + (size_t)wid * DM;
    const int c0 = lane * 4, c1 = 256 + lane * 4;
    ushort4 o0, o1;
    o0.x = f2b((v0.x - mean) * rs * sc[c0+0] + bi[c0+0]);
    o0.y = f2b((v0.y - mean) * rs * sc[c0+1] + bi[c0+1]);
    o0.z = f2b((v0.z - mean) * rs * sc[c0+2] + bi[c0+2]);
    o0.w = f2b((v0.w - mean) * rs * sc[c0+3] + bi[c0+3]);
    o1.x = f2b((v1.x - mean) * rs * sc[c1+0] + bi[c1+0]);
    o1.y = f2b((v1.y - mean) * rs * sc[c1+1] + bi[c1+1]);
    o1.z = f2b((v1.z - mean) * rs * sc[c1+2] + bi[c1+2]);
    o1.w = f2b((v1.w - mean) * rs * sc[c1+3] + bi[c1+3]);
    *(ushort4*)&hr[c0] = o0;
    *(ushort4*)&hr[c1] = o1;
}

// ---------------------------------------------------------------------------
// Dilated attention: qkv f32 [B*T x 1536] (q|k|v each H*64), o bf16 [B*T x 512]
// One wave per (b,h,t); lane = head dim element. <=16 keys at stride dil.
// ---------------------------------------------------------------------------
__global__ __launch_bounds__(256) void attn_kernel(
    const float* __restrict__ qkv, unsigned short* __restrict__ o, int dil)
{
    const int wid  = blockIdx.x * 4 + (threadIdx.x >> 6);  // 0 .. B*H*T-1
    const int lane = threadIdx.x & 63;
    const int t  = wid & (TSEQ - 1);
    const int bh = wid >> 11;          // T = 2048 = 2^11
    const int b  = bh >> 3, hh = bh & 7;
    const float q = qkv[(size_t)(b * TSEQ + t) * 1536 + hh * HD + lane] * 0.125f;
    const int nk = min(KATT, t / dil + 1);
    float scs[KATT], vcs[KATT];
#pragma unroll
    for (int s = 0; s < KATT; s++) {
        if (s < nk) {  // wave-uniform branch (t, dil uniform per wave)
            const float* kv = qkv + (size_t)(b * TSEQ + (t - s * dil)) * 1536 + hh * HD + lane;
            const float kval = kv[512];
            vcs[s] = kv[1024];
            float d = q * kval;
#pragma unroll
            for (int off = 32; off; off >>= 1) d += __shfl_xor(d, off, 64);
            scs[s] = d;                // replicated across lanes
        } else { scs[s] = -1e30f; vcs[s] = 0.0f; }
    }
    float m = scs[0];
#pragma unroll
    for (int s = 1; s < KATT; s++) m = fmaxf(m, scs[s]);
    float l = 0.0f, oa = 0.0f;
#pragma unroll
    for (int s = 0; s < KATT; s++) {
        const float p = expf(scs[s] - m);
        l += p;
        oa += p * vcs[s];
    }
    o[(size_t)(b * TSEQ + t) * DM + hh * HD + lane] = f2b(oa / l);
}

// ---------------------------------------------------------------------------
// GEMM: C[M,N] = A_bf16[M,K] * Bt_bf16[N,K]^T  (+ epilogue)
//   EPI 0: outf = C                       (qkv projection, no bias)
//   EPI 1: outf = xin + C + bias          (proj / w2, fused residual)
//   EPI 2: outb = bf16(gelu(C + bias))    (w1, exact gelu)
// 64x64 block tile, 4 waves, each wave 2x2 of 16x16x32 bf16 MFMA, BK=32.
// LDS row stride 40 shorts (80B): 16B-aligned, bank-balanced b128 reads.
// ---------------------------------------------------------------------------
template<int EPI>
__global__ __launch_bounds__(256) void gemm_kernel(
    const unsigned short* __restrict__ A,   // M x K
    const unsigned short* __restrict__ Bt,  // N x K
    const float* __restrict__ bias,         // N (or null)
    const float* __restrict__ xin,          // M x N residual in (or null)
    float* __restrict__ outf,               // f32 out
    unsigned short* __restrict__ outb,      // bf16 out
    int M, int N, int K)
{
    const int bn = blockIdx.x * 64;
    const int bm = blockIdx.y * 64;
    const int tid = threadIdx.x;
    const int wave = tid >> 6, lane = tid & 63;
    const int wm = (wave >> 1) * 32, wn = (wave & 1) * 32;
    const int ml = lane & 15, quad = lane >> 4;

    __shared__ unsigned short As[64 * 40];
    __shared__ unsigned short Bs[64 * 40];

    f32x4 acc[2][2] = {};

    const int srow = tid >> 2, sseg = tid & 3;   // staging: 64 rows x 4 16B segs
    for (int k0 = 0; k0 < K; k0 += 32) {
        const uint4 av = *(const uint4*)&A [(size_t)(bm + srow) * K + k0 + sseg * 8];
        const uint4 bv = *(const uint4*)&Bt[(size_t)(bn + srow) * K + k0 + sseg * 8];
        __syncthreads();
        *(uint4*)&As[srow * 40 + sseg * 8] = av;
        *(uint4*)&Bs[srow * 40 + sseg * 8] = bv;
        __syncthreads();
        const bf16x8 a0 = *(const bf16x8*)&As[(wm      + ml) * 40 + quad * 8];
        const bf16x8 a1 = *(const bf16x8*)&As[(wm + 16 + ml) * 40 + quad * 8];
        const bf16x8 b0 = *(const bf16x8*)&Bs[(wn      + ml) * 40 + quad * 8];
        const bf16x8 b1 = *(const bf16x8*)&Bs[(wn + 16 + ml) * 40 + quad * 8];
        acc[0][0] = __builtin_amdgcn_mfma_f32_16x16x32_bf16(a0, b0, acc[0][0], 0, 0, 0);
        acc[0][1] = __builtin_amdgcn_mfma_f32_16x16x32_bf16(a0, b1, acc[0][1], 0, 0, 0);
        acc[1][0] = __builtin_amdgcn_mfma_f32_16x16x32_bf16(a1, b0, acc[1][0], 0, 0, 0);
        acc[1][1] = __builtin_amdgcn_mfma_f32_16x16x32_bf16(a1, b1, acc[1][1], 0, 0, 0);
    }

#pragma unroll
    for (int i = 0; i < 2; i++)
#pragma unroll
        for (int j = 0; j < 2; j++)
#pragma unroll
            for (int r = 0; r < 4; r++) {
                const int row = bm + wm + i * 16 + quad * 4 + r;  // C/D: row=quad*4+reg
                const int col = bn + wn + j * 16 + ml;            // C/D: col=lane&15
                const float v = acc[i][j][r];
                const size_t idx = (size_t)row * N + col;
                if (EPI == 0) {
                    outf[idx] = v;
                } else if (EPI == 1) {
                    outf[idx] = xin[idx] + v + bias[col];
                } else {
                    const float u = v + bias[col];
                    const float g = 0.5f * u * (1.0f + erff(u * 0.70710678118654752f));
                    outb[idx] = f2b(g);
                }
            }
}

// ---------------------------------------------------------------------------
extern "C" void kernel_launch(void* const* d_in, const int* in_sizes, int n_in,
                              void* d_out, int out_size, void* d_ws, size_t ws_size,
                              hipStream_t stream)
{
    (void)in_sizes; (void)n_in; (void)out_size; (void)ws_size;
    const float* x_in   = (const float*)d_in[0];
    const float* ln1_s  = (const float*)d_in[1];
    const float* ln1_b  = (const float*)d_in[2];
    const float* qkv_w  = (const float*)d_in[3];
    const float* proj_w = (const float*)d_in[4];
    const float* proj_b = (const float*)d_in[5];
    const float* ln2_s  = (const float*)d_in[6];
    const float* ln2_b  = (const float*)d_in[7];
    const float* w1     = (const float*)d_in[8];
    const float* b1     = (const float*)d_in[9];
    const float* w2     = (const float*)d_in[10];
    const float* b2     = (const float*)d_in[11];

    // Workspace carve-up (all 256B aligned by construction)
    char* ws = (char*)d_ws;
    float*          xbuf = (float*)(ws);                        // 8 MB f32 x
    char*           Q    = ws + 8388608;                        // 25165824 B shared region
    float*          qkvb = (float*)Q;                           // qkv f32 [4096x1536]
    unsigned short* ubuf = (unsigned short*)Q;                  // u bf16 [4096x2048] (reuses qkv)
    unsigned short* hbuf = (unsigned short*)(ws + 33554432);    // h bf16 [4096x512]
    unsigned short* obuf = (unsigned short*)(ws + 37748736);    // o bf16 [4096x512]
    unsigned short* qkvT = (unsigned short*)(ws + 41943040);    // [3][1536x512]
    unsigned short* projT= (unsigned short*)(ws + 46661632);    // [3][512x512]
    unsigned short* w1T  = (unsigned short*)(ws + 48234496);    // [3][2048x512]
    unsigned short* w2T  = (unsigned short*)(ws + 54525952);    // [3][512x2048]

    // x working copy
    hipMemcpyAsync(xbuf, x_in, (size_t)MROWS * DM * sizeof(float),
                   hipMemcpyDeviceToDevice, stream);

    // Pre-transpose + bf16-convert all weights: Wt[n][k]
    transpose_w_kernel<<<dim3(1536/32, 512/32, 3),  dim3(32, 8), 0, stream>>>(qkv_w,  qkvT, 512, 1536);
    transpose_w_kernel<<<dim3( 512/32, 512/32, 3),  dim3(32, 8), 0, stream>>>(proj_w, projT, 512, 512);
    transpose_w_kernel<<<dim3(2048/32, 512/32, 3),  dim3(32, 8), 0, stream>>>(w1,     w1T,  512, 2048);
    transpose_w_kernel<<<dim3( 512/32, 2048/32, 3), dim3(32, 8), 0, stream>>>(w2,     w2T, 2048, 512);

    for (int d = 0; d < NDEPTH; d++) {
        const int dil = 1 << d;
        // LN1: x -> h (bf16)
        ln_kernel<<<MROWS / 4, 256, 0, stream>>>(xbuf, ln1_s + d * DM, ln1_b + d * DM, hbuf);
        // qkv = h @ qkv_w  (f32 out, no bias)
        gemm_kernel<0><<<dim3(1536/64, MROWS/64), 256, 0, stream>>>(
            hbuf, qkvT + (size_t)d * 1536 * 512, nullptr, nullptr, qkvb, nullptr,
            MROWS, 1536, 512);
        // dilated attention -> o (bf16)
        attn_kernel<<<(2 * NH * TSEQ) / 4, 256, 0, stream>>>(qkvb, obuf, dil);
        // x = x + o @ proj_w + proj_b
        gemm_kernel<1><<<dim3(512/64, MROWS/64), 256, 0, stream>>>(
            obuf, projT + (size_t)d * 512 * 512, proj_b + d * DM, xbuf, xbuf, nullptr,
            MROWS, 512, 512);
        // LN2: x -> h (bf16)
        ln_kernel<<<MROWS / 4, 256, 0, stream>>>(xbuf, ln2_s + d * DM, ln2_b + d * DM, hbuf);
        // u = gelu(h @ w1 + b1) (bf16 out; overwrites qkv region)
        gemm_kernel<2><<<dim3(2048/64, MROWS/64), 256, 0, stream>>>(
            hbuf, w1T + (size_t)d * 2048 * 512, b1 + d * 2048, nullptr, nullptr, ubuf,
            MROWS, 2048, 512);
        // x = x + u @ w2 + b2 ; final depth writes straight to d_out
        float* xout = (d == NDEPTH - 1) ? (float*)d_out : xbuf;
        gemm_kernel<1><<<dim3(512/64, MROWS/64), 256, 0, stream>>>(
            ubuf, w2T + (size_t)d * 512 * 2048, b2 + d * DM, xbuf, xout, nullptr,
            MROWS, 512, 2048);
    }
}

// Round 2
// 497.734 us; speedup vs baseline: 1.0916x; 1.0916x over previous
//
#include <hip/hip_runtime.h>
#include <math.h>

// Problem constants (B=2, T=2048, D=512, H=8, hd=64, K=16, DEPTH=3)
#define TSEQ   2048
#define DM     512
#define NH     8
#define HD     64
#define KATT   16
#define NDEPTH 3
#define MROWS  4096   // B*T

typedef __attribute__((ext_vector_type(8))) short bf16x8;
typedef __attribute__((ext_vector_type(4))) float f32x4;

// f32 -> bf16 (round-to-nearest-even), bit-level, no header dependency
static __device__ __forceinline__ unsigned short f2b(float f) {
    unsigned int u = __float_as_uint(f);
    unsigned int r = (u + 0x7fffu + ((u >> 16) & 1u)) >> 16;
    return (unsigned short)r;
}

// ---------------------------------------------------------------------------
// Weight prep: W f32 [K x N] (per depth) -> Wt bf16 [N x K]. grid.z = depth.
// ---------------------------------------------------------------------------
__global__ __launch_bounds__(256) void transpose_w_kernel(
    const float* __restrict__ W, unsigned short* __restrict__ Wt, int Kd, int Nd)
{
    __shared__ float tile[32][33];
    const int n0 = blockIdx.x * 32, k0 = blockIdx.y * 32;
    const size_t off = (size_t)blockIdx.z * Kd * Nd;
    const float* Wd = W + off;
    unsigned short* Wtd = Wt + off;
    const int tx = threadIdx.x, ty = threadIdx.y;
#pragma unroll
    for (int r = 0; r < 32; r += 8)
        tile[ty + r][tx] = Wd[(size_t)(k0 + ty + r) * Nd + (n0 + tx)];
    __syncthreads();
#pragma unroll
    for (int r = 0; r < 32; r += 8)
        Wtd[(size_t)(n0 + ty + r) * Kd + (k0 + tx)] = f2b(tile[tx][ty + r]);
}

// ---------------------------------------------------------------------------
// LayerNorm: x f32 [4096 x 512] -> h bf16 [4096 x 512]. One wave per row.
// ---------------------------------------------------------------------------
__global__ __launch_bounds__(256) void ln_kernel(
    const float* __restrict__ x, const float* __restrict__ sc,
    const float* __restrict__ bi, unsigned short* __restrict__ h)
{
    const int wid  = blockIdx.x * 4 + (threadIdx.x >> 6);
    const int lane = threadIdx.x & 63;
    const float* xr = x + (size_t)wid * DM;
    const float4 v0 = *(const float4*)&xr[lane * 4];
    const float4 v1 = *(const float4*)&xr[256 + lane * 4];
    float s = v0.x + v0.y + v0.z + v0.w + v1.x + v1.y + v1.z + v1.w;
    float q = v0.x*v0.x + v0.y*v0.y + v0.z*v0.z + v0.w*v0.w
            + v1.x*v1.x + v1.y*v1.y + v1.z*v1.z + v1.w*v1.w;
#pragma unroll
    for (int off = 32; off; off >>= 1) {
        s += __shfl_xor(s, off, 64);
        q += __shfl_xor(q, off, 64);
    }
    const float mean = s * (1.0f / DM);
    const float var  = q * (1.0f / DM) - mean * mean;
    const float rs   = rsqrtf(var + 1e-5f);
    unsigned short* hr = h + (size_t)wid * DM;
    const int c0 = lane * 4, c1 = 256 + lane * 4;
    ushort4 o0, o1;
    o0.x = f2b((v0.x - mean) * rs * sc[c0+0] + bi[c0+0]);
    o0.y = f2b((v0.y - mean) * rs * sc[c0+1] + bi[c0+1]);
    o0.z = f2b((v0.z - mean) * rs * sc[c0+2] + bi[c0+2]);
    o0.w = f2b((v0.w - mean) * rs * sc[c0+3] + bi[c0+3]);
    o1.x = f2b((v1.x - mean) * rs * sc[c1+0] + bi[c1+0]);
    o1.y = f2b((v1.y - mean) * rs * sc[c1+1] + bi[c1+1]);
    o1.z = f2b((v1.z - mean) * rs * sc[c1+2] + bi[c1+2]);
    o1.w = f2b((v1.w - mean) * rs * sc[c1+3] + bi[c1+3]);
    *(ushort4*)&hr[c0] = o0;
    *(ushort4*)&hr[c1] = o1;
}

// ---------------------------------------------------------------------------
// Dilated attention, shuffle-free dots.
// Block = 256 threads handles (b,h) and 16 consecutive queries t0..t0+15.
// Phase 1: thread (tq,s) [lane = (tq&3)*16 + s] computes the FULL 64-dim
//   dot(q_{t0+tq}, k_{t0+tq-s*dil}) in registers (no cross-lane reduction).
//   Softmax over s needs only 4 shfl_xor (within the 16-lane s-group).
//   Normalized p written to LDS.
// Phase 2: lane = head dim, wave iterates queries; coalesced 256B v-row
//   loads; p broadcast from LDS. Redundant k/v rows hit L1 (<=19 KB set).
// ---------------------------------------------------------------------------
__global__ __launch_bounds__(256) void attn_kernel(
    const float* __restrict__ qkv, unsigned short* __restrict__ o, int dil)
{
    const int blk  = blockIdx.x;
    const int tile = blk & (TSEQ / 16 - 1);   // 128 query tiles
    const int bh   = blk >> 7;
    const int b    = bh >> 3, hh = bh & 7;
    const int t0   = tile * 16;
    const int wave = threadIdx.x >> 6, lane = threadIdx.x & 63;
    const int tq   = wave * 4 + (lane >> 4);  // query 0..15
    const int s    = lane & 15;               // key slot 0..15
    const int t    = t0 + tq;
    const size_t base = (size_t)b * TSEQ * 1536 + (size_t)hh * HD;

    __shared__ float p_lds[16][17];

    // ---- phase 1: scores + softmax ----
    int row = t - s * dil;
    const bool valid = (row >= 0);
    row = max(row, 0);
    const float* kr = qkv + base + (size_t)row * 1536 + 512;
    const float* qr = qkv + base + (size_t)t * 1536;
    float dot = 0.0f;
#pragma unroll
    for (int j = 0; j < 16; j++) {
        const float4 k4 = *(const float4*)&kr[j * 4];
        const float4 q4 = *(const float4*)&qr[j * 4];
        dot += q4.x * k4.x + q4.y * k4.y + q4.z * k4.z + q4.w * k4.w;
    }
    const float sc = valid ? dot * 0.125f : -1e30f;
    float m = sc;
#pragma unroll
    for (int off = 1; off < 16; off <<= 1) m = fmaxf(m, __shfl_xor(m, off, 64));
    const float p = expf(sc - m);
    float l = p;
#pragma unroll
    for (int off = 1; off < 16; off <<= 1) l += __shfl_xor(l, off, 64);
    p_lds[tq][s] = p / l;
    __syncthreads();

    // ---- phase 2: o = sum_s p * v ----
#pragma unroll
    for (int qi = 0; qi < 4; qi++) {
        const int qq = qi * 4 + wave;
        const int tt = t0 + qq;
        float acc = 0.0f;
#pragma unroll
        for (int ss = 0; ss < KATT; ss++) {
            int vr = tt - ss * dil;
            const float pw = p_lds[qq][ss];   // exactly 0 for masked slots
            vr = max(vr, 0);
            acc += pw * qkv[base + (size_t)vr * 1536 + 1024 + lane];
        }
        o[(size_t)(b * TSEQ + tt) * DM + (size_t)hh * HD + lane] = f2b(acc);
    }
}

// ---------------------------------------------------------------------------
// GEMM: C[M,N] = A_bf16[M,K] * Bt_bf16[N,K]^T  (+ epilogue)
//   EPI 0: outf = C                       (qkv projection, no bias)
//   EPI 1: outf = xin + C + bias          (proj / w2, fused residual)
//   EPI 2: outb = bf16(gelu(C + bias))    (w1, exact gelu)
// 64x64 block tile, 4 waves, each wave 2x2 of 16x16x32 bf16 MFMA, BK=32.
// LDS row stride 40 shorts (80B): 16B-aligned, bank-balanced b128 reads.
// ---------------------------------------------------------------------------
template<int EPI>
__global__ __launch_bounds__(256) void gemm_kernel(
    const unsigned short* __restrict__ A,   // M x K
    const unsigned short* __restrict__ Bt,  // N x K
    const float* __restrict__ bias,         // N (or null)
    const float* __restrict__ xin,          // M x N residual in (or null)
    float* __restrict__ outf,               // f32 out
    unsigned short* __restrict__ outb,      // bf16 out
    int M, int N, int K)
{
    const int bn = blockIdx.x * 64;
    const int bm = blockIdx.y * 64;
    const int tid = threadIdx.x;
    const int wave = tid >> 6, lane = tid & 63;
    const int wm = (wave >> 1) * 32, wn = (wave & 1) * 32;
    const int ml = lane & 15, quad = lane >> 4;

    __shared__ unsigned short As[64 * 40];
    __shared__ unsigned short Bs[64 * 40];

    f32x4 acc[2][2] = {};

    const int srow = tid >> 2, sseg = tid & 3;   // staging: 64 rows x 4 16B segs
    for (int k0 = 0; k0 < K; k0 += 32) {
        const uint4 av = *(const uint4*)&A [(size_t)(bm + srow) * K + k0 + sseg * 8];
        const uint4 bv = *(const uint4*)&Bt[(size_t)(bn + srow) * K + k0 + sseg * 8];
        __syncthreads();
        *(uint4*)&As[srow * 40 + sseg * 8] = av;
        *(uint4*)&Bs[srow * 40 + sseg * 8] = bv;
        __syncthreads();
        const bf16x8 a0 = *(const bf16x8*)&As[(wm      + ml) * 40 + quad * 8];
        const bf16x8 a1 = *(const bf16x8*)&As[(wm + 16 + ml) * 40 + quad * 8];
        const bf16x8 b0 = *(const bf16x8*)&Bs[(wn      + ml) * 40 + quad * 8];
        const bf16x8 b1 = *(const bf16x8*)&Bs[(wn + 16 + ml) * 40 + quad * 8];
        acc[0][0] = __builtin_amdgcn_mfma_f32_16x16x32_bf16(a0, b0, acc[0][0], 0, 0, 0);
        acc[0][1] = __builtin_amdgcn_mfma_f32_16x16x32_bf16(a0, b1, acc[0][1], 0, 0, 0);
        acc[1][0] = __builtin_amdgcn_mfma_f32_16x16x32_bf16(a1, b0, acc[1][0], 0, 0, 0);
        acc[1][1] = __builtin_amdgcn_mfma_f32_16x16x32_bf16(a1, b1, acc[1][1], 0, 0, 0);
    }

#pragma unroll
    for (int i = 0; i < 2; i++)
#pragma unroll
        for (int j = 0; j < 2; j++)
#pragma unroll
            for (int r = 0; r < 4; r++) {
                const int row = bm + wm + i * 16 + quad * 4 + r;  // C/D: row=quad*4+reg
                const int col = bn + wn + j * 16 + ml;            // C/D: col=lane&15
                const float v = acc[i][j][r];
                const size_t idx = (size_t)row * N + col;
                if (EPI == 0) {
                    outf[idx] = v;
                } else if (EPI == 1) {
                    outf[idx] = xin[idx] + v + bias[col];
                } else {
                    const float u = v + bias[col];
                    const float g = 0.5f * u * (1.0f + erff(u * 0.70710678118654752f));
                    outb[idx] = f2b(g);
                }
            }
}

// ---------------------------------------------------------------------------
extern "C" void kernel_launch(void* const* d_in, const int* in_sizes, int n_in,
                              void* d_out, int out_size, void* d_ws, size_t ws_size,
                              hipStream_t stream)
{
    (void)in_sizes; (void)n_in; (void)out_size; (void)ws_size;
    const float* x_in   = (const float*)d_in[0];
    const float* ln1_s  = (const float*)d_in[1];
    const float* ln1_b  = (const float*)d_in[2];
    const float* qkv_w  = (const float*)d_in[3];
    const float* proj_w = (const float*)d_in[4];
    const float* proj_b = (const float*)d_in[5];
    const float* ln2_s  = (const float*)d_in[6];
    const float* ln2_b  = (const float*)d_in[7];
    const float* w1     = (const float*)d_in[8];
    const float* b1     = (const float*)d_in[9];
    const float* w2     = (const float*)d_in[10];
    const float* b2     = (const float*)d_in[11];

    // Workspace carve-up (all 256B aligned by construction)
    char* ws = (char*)d_ws;
    float*          xbuf = (float*)(ws);                        // 8 MB f32 x
    char*           Q    = ws + 8388608;                        // 25165824 B shared region
    float*          qkvb = (float*)Q;                           // qkv f32 [4096x1536]
    unsigned short* ubuf = (unsigned short*)Q;                  // u bf16 [4096x2048] (reuses qkv)
    unsigned short* hbuf = (unsigned short*)(ws + 33554432);    // h bf16 [4096x512]
    unsigned short* obuf = (unsigned short*)(ws + 37748736);    // o bf16 [4096x512]
    unsigned short* qkvT = (unsigned short*)(ws + 41943040);    // [3][1536x512]
    unsigned short* projT= (unsigned short*)(ws + 46661632);    // [3][512x512]
    unsigned short* w1T  = (unsigned short*)(ws + 48234496);    // [3][2048x512]
    unsigned short* w2T  = (unsigned short*)(ws + 54525952);    // [3][512x2048]

    // x working copy
    hipMemcpyAsync(xbuf, x_in, (size_t)MROWS * DM * sizeof(float),
                   hipMemcpyDeviceToDevice, stream);

    // Pre-transpose + bf16-convert all weights: Wt[n][k]
    transpose_w_kernel<<<dim3(1536/32, 512/32, 3),  dim3(32, 8), 0, stream>>>(qkv_w,  qkvT, 512, 1536);
    transpose_w_kernel<<<dim3( 512/32, 512/32, 3),  dim3(32, 8), 0, stream>>>(proj_w, projT, 512, 512);
    transpose_w_kernel<<<dim3(2048/32, 512/32, 3),  dim3(32, 8), 0, stream>>>(w1,     w1T,  512, 2048);
    transpose_w_kernel<<<dim3( 512/32, 2048/32, 3), dim3(32, 8), 0, stream>>>(w2,     w2T, 2048, 512);

    for (int d = 0; d < NDEPTH; d++) {
        const int dil = 1 << d;
        // LN1: x -> h (bf16)
        ln_kernel<<<MROWS / 4, 256, 0, stream>>>(xbuf, ln1_s + d * DM, ln1_b + d * DM, hbuf);
        // qkv = h @ qkv_w  (f32 out, no bias)
        gemm_kernel<0><<<dim3(1536/64, MROWS/64), 256, 0, stream>>>(
            hbuf, qkvT + (size_t)d * 1536 * 512, nullptr, nullptr, qkvb, nullptr,
            MROWS, 1536, 512);
        // dilated attention -> o (bf16)
        attn_kernel<<<2 * NH * (TSEQ / 16), 256, 0, stream>>>(qkvb, obuf, dil);
        // x = x + o @ proj_w + proj_b
        gemm_kernel<1><<<dim3(512/64, MROWS/64), 256, 0, stream>>>(
            obuf, projT + (size_t)d * 512 * 512, proj_b + d * DM, xbuf, xbuf, nullptr,
            MROWS, 512, 512);
        // LN2: x -> h (bf16)
        ln_kernel<<<MROWS / 4, 256, 0, stream>>>(xbuf, ln2_s + d * DM, ln2_b + d * DM, hbuf);
        // u = gelu(h @ w1 + b1) (bf16 out; overwrites qkv region)
        gemm_kernel<2><<<dim3(2048/64, MROWS/64), 256, 0, stream>>>(
            hbuf, w1T + (size_t)d * 2048 * 512, b1 + d * 2048, nullptr, nullptr, ubuf,
            MROWS, 2048, 512);
        // x = x + u @ w2 + b2 ; final depth writes straight to d_out
        float* xout = (d == NDEPTH - 1) ? (float*)d_out : xbuf;
        gemm_kernel<1><<<dim3(512/64, MROWS/64), 256, 0, stream>>>(
            ubuf, w2T + (size_t)d * 512 * 2048, b2 + d * DM, xbuf, xout, nullptr,
            MROWS, 512, 2048);
    }
}